// Round 3
// baseline (1033.867 us; speedup 1.0000x reference)
//
#include <hip/hip_runtime.h>
#include <math.h>

#pragma clang fp contract(off)

#define BB 8
#define AA 9
#define HH 64
#define WW 64
#define NN (HH*WW*AA)      /* 36864 */
#define PRE 6000
#define POST 300
#define SELCAP 8192
#define NMS_T 512
#define NQ 12              /* 512*12 = 6144 >= 6000 boxes/thread-chunks */
#define MW64 94            /* ceil(6000/64) mask words */

/* ---- workspace layout (bytes) ---- */
#define KEYS_OFF    0ULL
#define KEYS_BYTES  (BB*(size_t)NN*8)            /* 2,359,296 */
#define HIST_OFF    (KEYS_OFF + KEYS_BYTES)
#define HIST_BYTES  (BB*65536ULL*4)              /* 2,097,152 */
#define BINFO_OFF   (HIST_OFF + HIST_BYTES)
#define BINFO_BYTES (BB*2*4ULL)
#define SELCNT_OFF  (BINFO_OFF + BINFO_BYTES)
#define SELCNT_BYTES (BB*4ULL)
#define SELK_OFF    4456576ULL                   /* 8-aligned */
#define SELK_BYTES  (BB*(size_t)SELCAP*8)        /* 524,288 */
#define SELIDX_OFF  (SELK_OFF + SELK_BYTES)
#define SELIDX_BYTES (BB*(size_t)PRE*4)          /* 192,000 */
#define BOXES_OFF   5172864ULL                   /* 16-aligned */

/* 1) transform scores -> sortable keys + 16-bit-prefix histogram */
__global__ void keys_kernel(const float* __restrict__ scores,
                            unsigned long long* __restrict__ keys,
                            unsigned* __restrict__ hist) {
    int t = blockIdx.x * blockDim.x + threadIdx.x;
    if (t >= BB * NN) return;
    int b = t / NN;
    int i = t - b * NN;                 /* i = (h*64+w)*9 + a */
    int a = i % AA;
    int pix = i / AA;
    int wq = pix & 63;
    int hq = pix >> 6;
    float s = scores[((b * (2*AA) + AA + a) * HH + hq) * WW + wq];
    unsigned fb = __float_as_uint(s);
    unsigned u = (fb & 0x80000000u) ? ~fb : (fb | 0x80000000u); /* ascending = float ascending */
    unsigned k = ~u;                                            /* ascending = score descending */
    keys[t] = ((unsigned long long)k << 32) | (unsigned)i;
    atomicAdd(&hist[(b << 16) + (k >> 16)], 1u);
}

/* 2) per-batch scan of 65536 bins: find boundary bin T and count C1 below it */
__global__ __launch_bounds__(1024) void scan_kernel(const unsigned* __restrict__ hist,
                                                    unsigned* __restrict__ binfo) {
    int b = blockIdx.x;
    int tid = threadIdx.x;
    const unsigned* h = hist + ((size_t)b << 16);
    unsigned base = tid * 64;
    unsigned s = 0;
    for (int q = 0; q < 64; ++q) s += h[base + q];
    __shared__ unsigned psum[1024];
    psum[tid] = s;
    __syncthreads();
    for (int off = 1; off < 1024; off <<= 1) {
        unsigned v = (tid >= off) ? psum[tid - off] : 0u;
        __syncthreads();
        psum[tid] += v;
        __syncthreads();
    }
    unsigned incl = psum[tid];
    unsigned excl = incl - s;
    if (excl <= (PRE - 1) && (PRE - 1) < incl) {  /* rank 5999 lives in my chunk */
        unsigned c = excl;
        unsigned T = base;
        for (int q = 0; q < 64; ++q) {
            unsigned hv = h[base + q];
            if ((PRE - 1) < c + hv) { T = base + q; break; }
            c += hv;
        }
        binfo[b * 2 + 0] = T;
        binfo[b * 2 + 1] = c;
    }
}

/* 3) compact all keys with bin <= T (superset of top-6000, <= SELCAP).
   Wave-aggregated atomics (R1 fix: 547us -> off the profile). */
__global__ void compact_kernel(const unsigned long long* __restrict__ keys,
                               const unsigned* __restrict__ binfo,
                               unsigned* __restrict__ selcnt,
                               unsigned long long* __restrict__ selk) {
    int t = blockIdx.x * blockDim.x + threadIdx.x;
    bool valid = (t < BB * NN);
    int b = valid ? (t / NN) : 0;
    unsigned long long key = valid ? keys[t] : 0;
    unsigned bin = (unsigned)(key >> 48);
    unsigned T = binfo[b * 2 + 0];
    bool pred = valid && (bin <= T);

    unsigned long long sel = __ballot(pred);
    if (sel == 0) return;
    int lane = threadIdx.x & 63;
    int leader = __ffsll((long long)sel) - 1;
    unsigned base = 0;
    if (lane == leader) base = atomicAdd(&selcnt[b], (unsigned)__popcll(sel));
    base = __shfl(base, leader);
    if (pred) {
        unsigned pos = base + (unsigned)__popcll(sel & ((1ULL << lane) - 1ULL));
        if (pos < SELCAP) selk[((size_t)b << 13) + pos] = key;
    }
}

/* 4) per-batch bitonic sort of <=8192 keys in LDS; emit top-6000 indices in order */
__global__ __launch_bounds__(1024) void sort_kernel(const unsigned* __restrict__ selcnt,
                                                    const unsigned long long* __restrict__ selk,
                                                    unsigned* __restrict__ selidx) {
    __shared__ unsigned long long sk[SELCAP];
    int b = blockIdx.x;
    int tid = threadIdx.x;
    unsigned cnt = selcnt[b];
    if (cnt > SELCAP) cnt = SELCAP;
    for (int q = tid; q < SELCAP; q += 1024)
        sk[q] = (q < (int)cnt) ? selk[((size_t)b << 13) + q] : 0xFFFFFFFFFFFFFFFFULL;
    __syncthreads();
    for (unsigned k = 2; k <= SELCAP; k <<= 1) {
        for (unsigned j = k >> 1; j > 0; j >>= 1) {
            for (unsigned idx0 = tid; idx0 < SELCAP; idx0 += 1024) {
                unsigned ixj = idx0 ^ j;
                if (ixj > idx0) {
                    unsigned long long va = sk[idx0], vb = sk[ixj];
                    bool up = ((idx0 & k) == 0);
                    if ((va > vb) == up) { sk[idx0] = vb; sk[ixj] = va; }
                }
            }
            __syncthreads();
        }
    }
    for (int q = tid; q < PRE; q += 1024)
        selidx[b * PRE + q] = (unsigned)(sk[q] & 0xFFFFFFFFULL);
}

/* 5) decode + clip only the selected boxes (mirrors reference op order, no FMA) */
__global__ void box_kernel(const unsigned* __restrict__ selidx,
                           const float* __restrict__ deltas,
                           const float* __restrict__ anchors,
                           const int* __restrict__ imw,
                           const int* __restrict__ imh,
                           float4* __restrict__ boxes) {
    int t = blockIdx.x * blockDim.x + threadIdx.x;
    if (t >= BB * PRE) return;
    int b = t / PRE;
    unsigned idx = selidx[t];
    int a = idx % AA;
    int pix = idx / AA;
    int wq = pix & 63;
    int hq = pix >> 6;
    float sx = (float)(wq * 16);
    float sy = (float)(hq * 16);
    float ax1 = anchors[a * 4 + 0] + sx;
    float ay1 = anchors[a * 4 + 1] + sy;
    float ax2 = anchors[a * 4 + 2] + sx;
    float ay2 = anchors[a * 4 + 3] + sy;
    float aw = ax2 - ax1 + 1.0f;
    float ah = ay2 - ay1 + 1.0f;
    float acx = ax1 + 0.5f * aw;
    float acy = ay1 + 0.5f * ah;
    size_t dbase = ((size_t)b * (4*AA) + (size_t)a * 4) * (HH*WW) + (size_t)hq * WW + wq;
    float d0 = deltas[dbase + 0*(HH*WW)];
    float d1 = deltas[dbase + 1*(HH*WW)];
    float d2 = deltas[dbase + 2*(HH*WW)];
    float d3 = deltas[dbase + 3*(HH*WW)];
    float pcx = d0 * aw + acx;
    float pcy = d1 * ah + acy;
    float pw = expf(d2) * aw;
    float ph = expf(d3) * ah;
    float fw = (float)(imw[0] - 1);
    float fh = (float)(imh[0] - 1);
    float x1 = fminf(fmaxf(pcx - 0.5f * pw, 0.0f), fw);
    float y1 = fminf(fmaxf(pcy - 0.5f * ph, 0.0f), fh);
    float x2 = fminf(fmaxf(pcx + 0.5f * pw, 0.0f), fw);
    float y2 = fminf(fmaxf(pcy + 0.5f * ph, 0.0f), fh);
    boxes[t] = make_float4(x1, y1, x2, y2);
}

/* 6) greedy NMS, one block/batch, 512 threads (8 waves).
   R2 post-mortem: 400us = 300 iter x ~3200cyc (16-wave barrier + LDS atomics +
   latent find-next race). Redesign:
   - thread owns j = 512q + tid -> wave lanes cover contiguous 64-box span, so
     __ballot(sup) IS the 64-bit mask word: no atomics, lane0 plain-writes.
   - double-buffered mask (2x94 u64): read buf[p], every owner writes its word
     into buf[p^1] each iteration -> race-free with ONE barrier/iteration.
   - word-level skip: words fully <= i or already zero skip the IoU math. */
__global__ __launch_bounds__(NMS_T) void nms_kernel(const float4* __restrict__ boxes,
                                                    float* __restrict__ out) {
    int b = blockIdx.x;
    int tid = threadIdx.x;
    int wave = tid >> 6;
    int lane = tid & 63;
    __shared__ unsigned long long kb[2][MW64];
    float4 bx[NQ];
    float ar[NQ];
    #pragma unroll
    for (int q = 0; q < NQ; ++q) {
        int j = (q << 9) + tid;
        if (j < PRE) {
            bx[q] = boxes[b * PRE + j];
            ar[q] = (bx[q].z - bx[q].x + 1.0f) * (bx[q].w - bx[q].y + 1.0f);
        }
    }
    if (tid < MW64)
        kb[0][tid] = (tid == MW64 - 1) ? ((1ULL << (PRE - (MW64 - 1) * 64)) - 1ULL) : ~0ULL;
    __syncthreads();

    int cnt = 0, i = 0, p = 0;
    for (;;) {
        unsigned long long* cur = kb[p];
        unsigned long long* nxt = kb[p ^ 1];
        /* uniform find-next-set >= i (identical on all threads) */
        int w = i >> 6;
        unsigned long long m = cur[w] & (~0ULL << (i & 63));
        while (m == 0) { if (++w >= MW64) break; m = cur[w]; }
        if (m == 0) break;
        i = (w << 6) + (__ffsll((long long)m) - 1);

        float4 bi = boxes[b * PRE + i];
        if (tid == 0) {
            float* o = out + ((size_t)b * POST + cnt) * 5;
            o[0] = (float)b; o[1] = bi.x; o[2] = bi.y; o[3] = bi.z; o[4] = bi.w;
        }
        ++cnt;
        if (cnt >= POST) break;

        float ai = (bi.z - bi.x + 1.0f) * (bi.w - bi.y + 1.0f);
        #pragma unroll
        for (int q = 0; q < NQ; ++q) {
            int word = (q << 3) + wave;
            if (word >= MW64) continue;
            unsigned long long cw = cur[word];      /* lane-uniform read */
            unsigned long long sb = 0;
            /* word covers boxes [word*64, word*64+64): skip if none > i or all dead */
            if (cw != 0 && (word << 6) + 63 > i) {
                int j = (q << 9) + tid;             /* bit position = lane */
                bool sup = false;
                if (j > i && j < PRE) {
                    float xx1 = fmaxf(bi.x, bx[q].x);
                    float yy1 = fmaxf(bi.y, bx[q].y);
                    float xx2 = fminf(bi.z, bx[q].z);
                    float yy2 = fminf(bi.w, bx[q].w);
                    float iw = fmaxf(xx2 - xx1 + 1.0f, 0.0f);
                    float ih = fmaxf(yy2 - yy1 + 1.0f, 0.0f);
                    float inter = iw * ih;
                    float iou = inter / (ai + ar[q] - inter);
                    sup = (iou > 0.7f);
                }
                sb = __ballot(sup);
            }
            if (lane == 0) nxt[word] = cw & ~sb;
        }
        ++i;
        p ^= 1;
        __syncthreads();
    }
    /* zero-fill rows cnt..299 (out re-poisoned before every call) */
    for (int r = cnt + tid; r < POST; r += NMS_T) {
        float* o = out + ((size_t)b * POST + r) * 5;
        o[0] = 0.0f; o[1] = 0.0f; o[2] = 0.0f; o[3] = 0.0f; o[4] = 0.0f;
    }
}

extern "C" void kernel_launch(void* const* d_in, const int* in_sizes, int n_in,
                              void* d_out, int out_size, void* d_ws, size_t ws_size,
                              hipStream_t stream) {
    const float* scores  = (const float*)d_in[0];
    const float* deltas  = (const float*)d_in[1];
    const float* anchors = (const float*)d_in[2];
    const int*   imw     = (const int*)d_in[3];
    const int*   imh     = (const int*)d_in[4];
    float* out = (float*)d_out;
    char* ws = (char*)d_ws;

    unsigned long long* keys   = (unsigned long long*)(ws + KEYS_OFF);
    unsigned*           hist   = (unsigned*)(ws + HIST_OFF);
    unsigned*           binfo  = (unsigned*)(ws + BINFO_OFF);
    unsigned*           selcnt = (unsigned*)(ws + SELCNT_OFF);
    unsigned long long* selk   = (unsigned long long*)(ws + SELK_OFF);
    unsigned*           selidx = (unsigned*)(ws + SELIDX_OFF);
    float4*             boxes  = (float4*)(ws + BOXES_OFF);

    /* zero hist + binfo + selcnt (ws is poisoned before every call) */
    hipMemsetAsync(ws + HIST_OFF, 0, HIST_BYTES + BINFO_BYTES + SELCNT_BYTES, stream);

    keys_kernel<<<(BB * NN + 255) / 256, 256, 0, stream>>>(scores, keys, hist);
    scan_kernel<<<BB, 1024, 0, stream>>>(hist, binfo);
    compact_kernel<<<(BB * NN + 255) / 256, 256, 0, stream>>>(keys, binfo, selcnt, selk);
    sort_kernel<<<BB, 1024, 0, stream>>>(selcnt, selk, selidx);
    box_kernel<<<(BB * PRE + 255) / 256, 256, 0, stream>>>(selidx, deltas, anchors, imw, imh, boxes);
    nms_kernel<<<BB, NMS_T, 0, stream>>>(boxes, out);
}

// Round 4
// 560.463 us; speedup vs baseline: 1.8447x; 1.8447x over previous
//
#include <hip/hip_runtime.h>
#include <math.h>

#pragma clang fp contract(off)

#define BB 8
#define AA 9
#define HH 64
#define WW 64
#define NN (HH*WW*AA)      /* 36864 */
#define PRE 6000
#define POST 300
#define SELCAP 8192
#define WSZ 1024           /* NMS window size */
#define WW64 16            /* mask words per window */

/* ---- workspace layout (bytes) ---- */
#define KEYS_OFF    0ULL
#define KEYS_BYTES  (BB*(size_t)NN*8)            /* 2,359,296 */
#define HIST_OFF    (KEYS_OFF + KEYS_BYTES)
#define HIST_BYTES  (BB*65536ULL*4)              /* 2,097,152 */
#define BINFO_OFF   (HIST_OFF + HIST_BYTES)
#define BINFO_BYTES (BB*2*4ULL)
#define SELCNT_OFF  (BINFO_OFF + BINFO_BYTES)
#define SELCNT_BYTES (BB*4ULL)
#define SELK_OFF    4456576ULL                   /* 8-aligned */
#define SELK_BYTES  (BB*(size_t)SELCAP*8)        /* 524,288 */
#define SELIDX_OFF  (SELK_OFF + SELK_BYTES)
#define SELIDX_BYTES (BB*(size_t)PRE*4)          /* 192,000 */
#define BOXES_OFF   5172864ULL                   /* 16-aligned */

/* 1) transform scores -> sortable keys + 16-bit-prefix histogram */
__global__ void keys_kernel(const float* __restrict__ scores,
                            unsigned long long* __restrict__ keys,
                            unsigned* __restrict__ hist) {
    int t = blockIdx.x * blockDim.x + threadIdx.x;
    if (t >= BB * NN) return;
    int b = t / NN;
    int i = t - b * NN;                 /* i = (h*64+w)*9 + a */
    int a = i % AA;
    int pix = i / AA;
    int wq = pix & 63;
    int hq = pix >> 6;
    float s = scores[((b * (2*AA) + AA + a) * HH + hq) * WW + wq];
    unsigned fb = __float_as_uint(s);
    unsigned u = (fb & 0x80000000u) ? ~fb : (fb | 0x80000000u); /* ascending = float ascending */
    unsigned k = ~u;                                            /* ascending = score descending */
    keys[t] = ((unsigned long long)k << 32) | (unsigned)i;
    atomicAdd(&hist[(b << 16) + (k >> 16)], 1u);
}

/* 2) per-batch scan of 65536 bins: find boundary bin T and count C1 below it */
__global__ __launch_bounds__(1024) void scan_kernel(const unsigned* __restrict__ hist,
                                                    unsigned* __restrict__ binfo) {
    int b = blockIdx.x;
    int tid = threadIdx.x;
    const unsigned* h = hist + ((size_t)b << 16);
    unsigned base = tid * 64;
    unsigned s = 0;
    for (int q = 0; q < 64; ++q) s += h[base + q];
    __shared__ unsigned psum[1024];
    psum[tid] = s;
    __syncthreads();
    for (int off = 1; off < 1024; off <<= 1) {
        unsigned v = (tid >= off) ? psum[tid - off] : 0u;
        __syncthreads();
        psum[tid] += v;
        __syncthreads();
    }
    unsigned incl = psum[tid];
    unsigned excl = incl - s;
    if (excl <= (PRE - 1) && (PRE - 1) < incl) {  /* rank 5999 lives in my chunk */
        unsigned c = excl;
        unsigned T = base;
        for (int q = 0; q < 64; ++q) {
            unsigned hv = h[base + q];
            if ((PRE - 1) < c + hv) { T = base + q; break; }
            c += hv;
        }
        binfo[b * 2 + 0] = T;
        binfo[b * 2 + 1] = c;
    }
}

/* 3) compact all keys with bin <= T (superset of top-6000, <= SELCAP).
   Wave-aggregated atomics (R1 fix: 547us -> off the profile). */
__global__ void compact_kernel(const unsigned long long* __restrict__ keys,
                               const unsigned* __restrict__ binfo,
                               unsigned* __restrict__ selcnt,
                               unsigned long long* __restrict__ selk) {
    int t = blockIdx.x * blockDim.x + threadIdx.x;
    bool valid = (t < BB * NN);
    int b = valid ? (t / NN) : 0;
    unsigned long long key = valid ? keys[t] : 0;
    unsigned bin = (unsigned)(key >> 48);
    unsigned T = binfo[b * 2 + 0];
    bool pred = valid && (bin <= T);

    unsigned long long sel = __ballot(pred);
    if (sel == 0) return;
    int lane = threadIdx.x & 63;
    int leader = __ffsll((long long)sel) - 1;
    unsigned base = 0;
    if (lane == leader) base = atomicAdd(&selcnt[b], (unsigned)__popcll(sel));
    base = __shfl(base, leader);
    if (pred) {
        unsigned pos = base + (unsigned)__popcll(sel & ((1ULL << lane) - 1ULL));
        if (pos < SELCAP) selk[((size_t)b << 13) + pos] = key;
    }
}

/* 4) per-batch bitonic sort of <=8192 keys in LDS; emit top-6000 indices in order */
__global__ __launch_bounds__(1024) void sort_kernel(const unsigned* __restrict__ selcnt,
                                                    const unsigned long long* __restrict__ selk,
                                                    unsigned* __restrict__ selidx) {
    __shared__ unsigned long long sk[SELCAP];
    int b = blockIdx.x;
    int tid = threadIdx.x;
    unsigned cnt = selcnt[b];
    if (cnt > SELCAP) cnt = SELCAP;
    for (int q = tid; q < SELCAP; q += 1024)
        sk[q] = (q < (int)cnt) ? selk[((size_t)b << 13) + q] : 0xFFFFFFFFFFFFFFFFULL;
    __syncthreads();
    for (unsigned k = 2; k <= SELCAP; k <<= 1) {
        for (unsigned j = k >> 1; j > 0; j >>= 1) {
            for (unsigned idx0 = tid; idx0 < SELCAP; idx0 += 1024) {
                unsigned ixj = idx0 ^ j;
                if (ixj > idx0) {
                    unsigned long long va = sk[idx0], vb = sk[ixj];
                    bool up = ((idx0 & k) == 0);
                    if ((va > vb) == up) { sk[idx0] = vb; sk[ixj] = va; }
                }
            }
            __syncthreads();
        }
    }
    for (int q = tid; q < PRE; q += 1024)
        selidx[b * PRE + q] = (unsigned)(sk[q] & 0xFFFFFFFFULL);
}

/* 5) decode + clip only the selected boxes (mirrors reference op order, no FMA) */
__global__ void box_kernel(const unsigned* __restrict__ selidx,
                           const float* __restrict__ deltas,
                           const float* __restrict__ anchors,
                           const int* __restrict__ imw,
                           const int* __restrict__ imh,
                           float4* __restrict__ boxes) {
    int t = blockIdx.x * blockDim.x + threadIdx.x;
    if (t >= BB * PRE) return;
    int b = t / PRE;
    unsigned idx = selidx[t];
    int a = idx % AA;
    int pix = idx / AA;
    int wq = pix & 63;
    int hq = pix >> 6;
    float sx = (float)(wq * 16);
    float sy = (float)(hq * 16);
    float ax1 = anchors[a * 4 + 0] + sx;
    float ay1 = anchors[a * 4 + 1] + sy;
    float ax2 = anchors[a * 4 + 2] + sx;
    float ay2 = anchors[a * 4 + 3] + sy;
    float aw = ax2 - ax1 + 1.0f;
    float ah = ay2 - ay1 + 1.0f;
    float acx = ax1 + 0.5f * aw;
    float acy = ay1 + 0.5f * ah;
    size_t dbase = ((size_t)b * (4*AA) + (size_t)a * 4) * (HH*WW) + (size_t)hq * WW + wq;
    float d0 = deltas[dbase + 0*(HH*WW)];
    float d1 = deltas[dbase + 1*(HH*WW)];
    float d2 = deltas[dbase + 2*(HH*WW)];
    float d3 = deltas[dbase + 3*(HH*WW)];
    float pcx = d0 * aw + acx;
    float pcy = d1 * ah + acy;
    float pw = expf(d2) * aw;
    float ph = expf(d3) * ah;
    float fw = (float)(imw[0] - 1);
    float fh = (float)(imh[0] - 1);
    float x1 = fminf(fmaxf(pcx - 0.5f * pw, 0.0f), fw);
    float y1 = fminf(fmaxf(pcy - 0.5f * ph, 0.0f), fh);
    float x2 = fminf(fmaxf(pcx + 0.5f * pw, 0.0f), fw);
    float y2 = fminf(fmaxf(pcy + 0.5f * ph, 0.0f), fh);
    boxes[t] = make_float4(x1, y1, x2, y2);
}

/* Exact, division-free replica of the reference suppression test:
   RN_f32(inter/uni) > 0.7f  <=>  inter/uni >= mid  (mid = 0.7f + 2^-25;
   tie rounds-to-even to the UPPER neighbor, hence >=)
                            <=>  (double)inter >= mid * (double)uni
   mid has a 25-bit mantissa, uni 24 bits -> the f64 product is EXACT. */
__device__ __forceinline__ bool iou_gt(float ax1, float ay1, float ax2, float ay2, float aa,
                                       float bx1_, float by1_, float bx2_, float by2_, float ab) {
    float xx1 = fmaxf(ax1, bx1_);
    float yy1 = fmaxf(ay1, by1_);
    float xx2 = fminf(ax2, bx2_);
    float yy2 = fminf(ay2, by2_);
    float iw = fmaxf(xx2 - xx1 + 1.0f, 0.0f);
    float ih = fmaxf(yy2 - yy1 + 1.0f, 0.0f);
    float inter = iw * ih;
    float uni = (aa + ab) - inter;
    return (double)inter >= 0x1.666667p-1 * (double)uni;
}

/* 6) windowed greedy NMS, one block/batch, 256 threads (4 waves).
   R2/R3 post-mortem: any all-6000-IoU-per-iteration scheme is VALU-bound at
   >=150us on 8 CUs (R2: VALUBusy 86% on active CUs); R3 added 12 dependent
   ~120cyc LDS reads/iter -> 753us. Here: 1024-box window, boxes in REGISTERS
   (4/thread), find-next via one 16-address LDS read + ballot, ballot = mask
   word (no atomics), double-buffered 16-word mask, one barrier/iter.
   Window advance (rare): reload + suppress vs kept-list in LDS. */
__global__ __launch_bounds__(256) void nms_kernel(const float4* __restrict__ boxes,
                                                  float* __restrict__ out) {
    int b = blockIdx.x;
    int tid = threadIdx.x;
    int wave = tid >> 6;
    int lane = tid & 63;
    __shared__ float wb[5][WSZ];          /* x1,y1,x2,y2,area */
    __shared__ float kb[POST][5];         /* kept boxes */
    __shared__ unsigned long long msk[2][WW64];

    float cx1[4], cy1[4], cx2[4], cy2[4], car[4];

    int base = 0, K = 0, cnt = 0, cur = 0, p = 0;

    /* initial window */
    #pragma unroll
    for (int q = 0; q < 4; ++q) {
        int c = (q << 8) + tid;
        int g = base + c; if (g > PRE - 1) g = PRE - 1;
        float4 v = boxes[b * PRE + g];
        cx1[q] = v.x; cy1[q] = v.y; cx2[q] = v.z; cy2[q] = v.w;
        car[q] = (v.z - v.x + 1.0f) * (v.w - v.y + 1.0f);
        wb[0][c] = v.x; wb[1][c] = v.y; wb[2][c] = v.z; wb[3][c] = v.w; wb[4][c] = car[q];
    }
    if (tid < WW64) msk[0][tid] = ~0ULL;  /* first window fully valid (PRE>WSZ) */
    __syncthreads();

    for (;;) {
        /* uniform find-next-live >= cur: one LDS read (lane&15 -> word) + ballot */
        int w = lane & 15;
        unsigned long long v = msk[p][w];
        int lo = w << 6;
        if (lo + 64 <= cur) v = 0;
        else if (lo < cur) v &= (~0ULL << (cur - lo));
        unsigned wm = (unsigned)__ballot(v != 0) & 0xFFFFu;

        if (wm == 0) {
            /* window exhausted -> advance (or done) */
            base += WSZ;
            if (base >= PRE) break;
            __syncthreads();                   /* seal msk/wb before rewrite */
            #pragma unroll
            for (int q = 0; q < 4; ++q) {
                int c = (q << 8) + tid;
                int g = base + c; if (g > PRE - 1) g = PRE - 1;
                float4 vv = boxes[b * PRE + g];
                cx1[q] = vv.x; cy1[q] = vv.y; cx2[q] = vv.z; cy2[q] = vv.w;
                car[q] = (vv.z - vv.x + 1.0f) * (vv.w - vv.y + 1.0f);
                wb[0][c] = vv.x; wb[1][c] = vv.y; wb[2][c] = vv.z; wb[3][c] = vv.w; wb[4][c] = car[q];
            }
            int valid = PRE - base; if (valid > WSZ) valid = WSZ;
            bool dead0 = false, dead1 = false, dead2 = false, dead3 = false;
            for (int k = 0; k < K; ++k) {       /* suppress new window vs all kept */
                float kx1 = kb[k][0], ky1 = kb[k][1], kx2 = kb[k][2], ky2 = kb[k][3], ka = kb[k][4];
                dead0 = dead0 || iou_gt(kx1,ky1,kx2,ky2,ka, cx1[0],cy1[0],cx2[0],cy2[0],car[0]);
                dead1 = dead1 || iou_gt(kx1,ky1,kx2,ky2,ka, cx1[1],cy1[1],cx2[1],cy2[1],car[1]);
                dead2 = dead2 || iou_gt(kx1,ky1,kx2,ky2,ka, cx1[2],cy1[2],cx2[2],cy2[2],car[2]);
                dead3 = dead3 || iou_gt(kx1,ky1,kx2,ky2,ka, cx1[3],cy1[3],cx2[3],cy2[3],car[3]);
            }
            #pragma unroll
            for (int q = 0; q < 4; ++q) {
                int c = (q << 8) + tid;
                bool dq = (q == 0) ? dead0 : (q == 1) ? dead1 : (q == 2) ? dead2 : dead3;
                bool alive = (c < valid) && !dq;
                unsigned long long ab = __ballot(alive);
                if (lane == 0) msk[p][(q << 2) + wave] = ab;
            }
            cur = 0;
            __syncthreads();
            continue;
        }

        int w0 = __ffs(wm) - 1;
        unsigned long long vv = __shfl(v, w0);
        int l = (w0 << 6) + (__ffsll((long long)vv) - 1);

        /* box l from LDS window (broadcast reads) */
        float bx1 = wb[0][l], by1 = wb[1][l], bx2 = wb[2][l], by2 = wb[3][l], ba = wb[4][l];

        if (tid < 5) {
            float val = (tid == 0) ? (float)b : (tid == 1) ? bx1 : (tid == 2) ? by1
                       : (tid == 3) ? bx2 : by2;
            out[((size_t)b * POST + cnt) * 5 + tid] = val;
        }
        if (tid == 0) {
            kb[cnt][0] = bx1; kb[cnt][1] = by1; kb[cnt][2] = bx2; kb[cnt][3] = by2; kb[cnt][4] = ba;
        }
        ++K; ++cnt;
        if (cnt >= POST) break;

        /* suppression: ballot IS the mask word; write into the other buffer */
        #pragma unroll
        for (int q = 0; q < 4; ++q) {
            int c = (q << 8) + tid;
            bool sup = (c > l) && iou_gt(bx1,by1,bx2,by2,ba,
                                         cx1[q],cy1[q],cx2[q],cy2[q],car[q]);
            unsigned long long sb = __ballot(sup);
            unsigned long long cw = msk[p][(q << 2) + wave];
            if (lane == 0) msk[p ^ 1][(q << 2) + wave] = cw & ~sb;
        }
        cur = l + 1;
        p ^= 1;
        __syncthreads();
    }

    /* zero-fill rows cnt..299 (out re-poisoned before every call) */
    for (int r = cnt + tid; r < POST; r += 256) {
        float* o = out + ((size_t)b * POST + r) * 5;
        o[0] = 0.0f; o[1] = 0.0f; o[2] = 0.0f; o[3] = 0.0f; o[4] = 0.0f;
    }
}

extern "C" void kernel_launch(void* const* d_in, const int* in_sizes, int n_in,
                              void* d_out, int out_size, void* d_ws, size_t ws_size,
                              hipStream_t stream) {
    const float* scores  = (const float*)d_in[0];
    const float* deltas  = (const float*)d_in[1];
    const float* anchors = (const float*)d_in[2];
    const int*   imw     = (const int*)d_in[3];
    const int*   imh     = (const int*)d_in[4];
    float* out = (float*)d_out;
    char* ws = (char*)d_ws;

    unsigned long long* keys   = (unsigned long long*)(ws + KEYS_OFF);
    unsigned*           hist   = (unsigned*)(ws + HIST_OFF);
    unsigned*           binfo  = (unsigned*)(ws + BINFO_OFF);
    unsigned*           selcnt = (unsigned*)(ws + SELCNT_OFF);
    unsigned long long* selk   = (unsigned long long*)(ws + SELK_OFF);
    unsigned*           selidx = (unsigned*)(ws + SELIDX_OFF);
    float4*             boxes  = (float4*)(ws + BOXES_OFF);

    /* zero hist + binfo + selcnt (ws is poisoned before every call) */
    hipMemsetAsync(ws + HIST_OFF, 0, HIST_BYTES + BINFO_BYTES + SELCNT_BYTES, stream);

    keys_kernel<<<(BB * NN + 255) / 256, 256, 0, stream>>>(scores, keys, hist);
    scan_kernel<<<BB, 1024, 0, stream>>>(hist, binfo);
    compact_kernel<<<(BB * NN + 255) / 256, 256, 0, stream>>>(keys, binfo, selcnt, selk);
    sort_kernel<<<BB, 1024, 0, stream>>>(selcnt, selk, selidx);
    box_kernel<<<(BB * PRE + 255) / 256, 256, 0, stream>>>(selidx, deltas, anchors, imw, imh, boxes);
    nms_kernel<<<BB, 256, 0, stream>>>(boxes, out);
}

// Round 5
// 398.482 us; speedup vs baseline: 2.5945x; 1.4065x over previous
//
#include <hip/hip_runtime.h>
#include <math.h>

#pragma clang fp contract(off)

#define BB 8
#define AA 9
#define HH 64
#define WW 64
#define NN (HH*WW*AA)      /* 36864 */
#define PRE 6000
#define POST 300
#define SELCAP 8192
#define NMS_T 512          /* 8 waves */
#define NQ 2               /* window chunks per thread: 512*2 = 1024 */
#define WSZ 1024
#define WW64 16            /* mask words per window */

/* ---- workspace layout (bytes) ---- */
#define KEYS_OFF    0ULL
#define KEYS_BYTES  (BB*(size_t)NN*8)            /* 2,359,296 */
#define HIST_OFF    (KEYS_OFF + KEYS_BYTES)
#define HIST_BYTES  (BB*65536ULL*4)              /* 2,097,152 */
#define BINFO_OFF   (HIST_OFF + HIST_BYTES)
#define BINFO_BYTES (BB*2*4ULL)
#define SELCNT_OFF  (BINFO_OFF + BINFO_BYTES)
#define SELCNT_BYTES (BB*4ULL)
#define SELK_OFF    4456576ULL                   /* 8-aligned */
#define SELK_BYTES  (BB*(size_t)SELCAP*8)        /* 524,288 */
#define SELIDX_OFF  (SELK_OFF + SELK_BYTES)
#define SELIDX_BYTES (BB*(size_t)PRE*4)          /* 192,000 */
#define BOXES_OFF   5172864ULL                   /* 16-aligned */

/* 1) transform scores -> sortable keys + 16-bit-prefix histogram */
__global__ void keys_kernel(const float* __restrict__ scores,
                            unsigned long long* __restrict__ keys,
                            unsigned* __restrict__ hist) {
    int t = blockIdx.x * blockDim.x + threadIdx.x;
    if (t >= BB * NN) return;
    int b = t / NN;
    int i = t - b * NN;                 /* i = (h*64+w)*9 + a */
    int a = i % AA;
    int pix = i / AA;
    int wq = pix & 63;
    int hq = pix >> 6;
    float s = scores[((b * (2*AA) + AA + a) * HH + hq) * WW + wq];
    unsigned fb = __float_as_uint(s);
    unsigned u = (fb & 0x80000000u) ? ~fb : (fb | 0x80000000u);
    unsigned k = ~u;                    /* ascending = score descending */
    keys[t] = ((unsigned long long)k << 32) | (unsigned)i;
    atomicAdd(&hist[(b << 16) + (k >> 16)], 1u);
}

/* 2) per-batch scan of 65536 bins: find boundary bin T */
__global__ __launch_bounds__(1024) void scan_kernel(const unsigned* __restrict__ hist,
                                                    unsigned* __restrict__ binfo) {
    int b = blockIdx.x;
    int tid = threadIdx.x;
    const unsigned* h = hist + ((size_t)b << 16);
    unsigned base = tid * 64;
    unsigned s = 0;
    for (int q = 0; q < 64; ++q) s += h[base + q];
    __shared__ unsigned psum[1024];
    psum[tid] = s;
    __syncthreads();
    for (int off = 1; off < 1024; off <<= 1) {
        unsigned v = (tid >= off) ? psum[tid - off] : 0u;
        __syncthreads();
        psum[tid] += v;
        __syncthreads();
    }
    unsigned incl = psum[tid];
    unsigned excl = incl - s;
    if (excl <= (PRE - 1) && (PRE - 1) < incl) {
        unsigned c = excl;
        unsigned T = base;
        for (int q = 0; q < 64; ++q) {
            unsigned hv = h[base + q];
            if ((PRE - 1) < c + hv) { T = base + q; break; }
            c += hv;
        }
        binfo[b * 2 + 0] = T;
        binfo[b * 2 + 1] = c;
    }
}

/* 3) compact all keys with bin <= T (superset of top-6000, <= SELCAP).
   Wave-aggregated atomics (R1 fix). Order arbitrary — rank_kernel fixes it. */
__global__ void compact_kernel(const unsigned long long* __restrict__ keys,
                               const unsigned* __restrict__ binfo,
                               unsigned* __restrict__ selcnt,
                               unsigned long long* __restrict__ selk) {
    int t = blockIdx.x * blockDim.x + threadIdx.x;
    bool valid = (t < BB * NN);
    int b = valid ? (t / NN) : 0;
    unsigned long long key = valid ? keys[t] : 0;
    unsigned bin = (unsigned)(key >> 48);
    unsigned T = binfo[b * 2 + 0];
    bool pred = valid && (bin <= T);

    unsigned long long sel = __ballot(pred);
    if (sel == 0) return;
    int lane = threadIdx.x & 63;
    int leader = __ffsll((long long)sel) - 1;
    unsigned base = 0;
    if (lane == leader) base = atomicAdd(&selcnt[b], (unsigned)__popcll(sel));
    base = __shfl(base, leader);
    if (pred) {
        unsigned pos = base + (unsigned)__popcll(sel & ((1ULL << lane) - 1ULL));
        if (pos < SELCAP) selk[((size_t)b << 13) + pos] = key;
    }
}

/* 4) exact rank by brute-force count (replaces 8192-key bitonic sort).
   R4 post-mortem: bitonic = 91 phases x 256KB LDS traffic on 8 CUs ~ 78us.
   Keys distinct -> rank = #smaller is a permutation. 256 blocks (full GPU),
   keys staged in LDS (broadcast reads), ~12us. */
__global__ __launch_bounds__(256) void rank_kernel(const unsigned* __restrict__ selcnt,
                                                   const unsigned long long* __restrict__ selk,
                                                   unsigned* __restrict__ selidx) {
    __shared__ unsigned long long sk[SELCAP];
    int b = blockIdx.x >> 5;           /* 32 blocks per batch */
    int chunk = blockIdx.x & 31;
    unsigned cnt = selcnt[b];
    if (cnt > SELCAP) cnt = SELCAP;
    const unsigned long long* src = selk + ((size_t)b << 13);
    for (int i = threadIdx.x; i < (int)cnt; i += 256) sk[i] = src[i];
    __syncthreads();
    int s = (chunk << 8) + threadIdx.x;
    if (s >= (int)cnt) return;
    unsigned long long k0 = sk[s];
    int rank = 0;
    for (int i = 0; i < (int)cnt; ++i) rank += (sk[i] < k0) ? 1 : 0;
    if (rank < PRE) selidx[b * PRE + rank] = (unsigned)(k0 & 0xFFFFFFFFULL);
}

/* 5) decode + clip only the selected boxes (mirrors reference op order, no FMA) */
__global__ void box_kernel(const unsigned* __restrict__ selidx,
                           const float* __restrict__ deltas,
                           const float* __restrict__ anchors,
                           const int* __restrict__ imw,
                           const int* __restrict__ imh,
                           float4* __restrict__ boxes) {
    int t = blockIdx.x * blockDim.x + threadIdx.x;
    if (t >= BB * PRE) return;
    int b = t / PRE;
    unsigned idx = selidx[t];
    int a = idx % AA;
    int pix = idx / AA;
    int wq = pix & 63;
    int hq = pix >> 6;
    float sx = (float)(wq * 16);
    float sy = (float)(hq * 16);
    float ax1 = anchors[a * 4 + 0] + sx;
    float ay1 = anchors[a * 4 + 1] + sy;
    float ax2 = anchors[a * 4 + 2] + sx;
    float ay2 = anchors[a * 4 + 3] + sy;
    float aw = ax2 - ax1 + 1.0f;
    float ah = ay2 - ay1 + 1.0f;
    float acx = ax1 + 0.5f * aw;
    float acy = ay1 + 0.5f * ah;
    size_t dbase = ((size_t)b * (4*AA) + (size_t)a * 4) * (HH*WW) + (size_t)hq * WW + wq;
    float d0 = deltas[dbase + 0*(HH*WW)];
    float d1 = deltas[dbase + 1*(HH*WW)];
    float d2 = deltas[dbase + 2*(HH*WW)];
    float d3 = deltas[dbase + 3*(HH*WW)];
    float pcx = d0 * aw + acx;
    float pcy = d1 * ah + acy;
    float pw = expf(d2) * aw;
    float ph = expf(d3) * ah;
    float fw = (float)(imw[0] - 1);
    float fh = (float)(imh[0] - 1);
    float x1 = fminf(fmaxf(pcx - 0.5f * pw, 0.0f), fw);
    float y1 = fminf(fmaxf(pcy - 0.5f * ph, 0.0f), fh);
    float x2 = fminf(fmaxf(pcx + 0.5f * pw, 0.0f), fw);
    float y2 = fminf(fmaxf(pcy + 0.5f * ph, 0.0f), fh);
    boxes[t] = make_float4(x1, y1, x2, y2);
}

/* Exact, division-free replica of the reference suppression test:
   RN_f32(inter/uni) > 0.7f  <=>  (double)inter >= (0.7f + 2^-25) * (double)uni
   (25-bit x 24-bit mantissas -> f64 product exact; tie rounds-to-even UP). */
__device__ __forceinline__ bool iou_gt(float ax1, float ay1, float ax2, float ay2, float aa,
                                       float bx1_, float by1_, float bx2_, float by2_, float ab) {
    float xx1 = fmaxf(ax1, bx1_);
    float yy1 = fmaxf(ay1, by1_);
    float xx2 = fminf(ax2, bx2_);
    float yy2 = fminf(ay2, by2_);
    float iw = fmaxf(xx2 - xx1 + 1.0f, 0.0f);
    float ih = fmaxf(yy2 - yy1 + 1.0f, 0.0f);
    float inter = iw * ih;
    float uni = (aa + ab) - inter;
    return (double)inter >= 0x1.666667p-1 * (double)uni;
}

/* select among 8 uniform values by per-lane index (7 cndmasks) */
__device__ __forceinline__ int sel8(int k, int c0, int c1, int c2, int c3,
                                    int c4, int c5, int c6, int c7) {
    int r = c0;
    r = (k == 1) ? c1 : r; r = (k == 2) ? c2 : r; r = (k == 3) ? c3 : r;
    r = (k == 4) ? c4 : r; r = (k == 5) ? c5 : r; r = (k == 6) ? c6 : r;
    r = (k == 7) ? c7 : r;
    return r;
}

/* 6) multi-keep speculative greedy NMS, one block/batch, 512 threads.
   R4 post-mortem: ~2230cyc/keep (find LDS + shfl + box reads + per-iter global
   store vmcnt drain + barrier). Here: per round take up to 8 candidates = ALL
   live boxes in the first two nonzero mask words (complete coverage => greedy
   decisions in that range are final), 28 pair-IoUs in parallel (1 lane/pair,
   one ballot), scalar greedy chain over the 28-bit relation, ONE suppression
   pass + ONE barrier for all keeps. out written once at the end. */
__global__ __launch_bounds__(NMS_T) void nms_kernel(const float4* __restrict__ boxes,
                                                    float* __restrict__ out) {
    int b = blockIdx.x;
    int tid = threadIdx.x;
    int wave = tid >> 6;
    int lane = tid & 63;
    __shared__ float wb[5][WSZ];          /* x1,y1,x2,y2,area */
    __shared__ float kb[POST][5];         /* kept boxes */
    __shared__ unsigned long long msk[2][WW64];

    float cx1[NQ], cy1[NQ], cx2[NQ], cy2[NQ], car[NQ];

    int base = 0, cnt = 0, cur = 0, p = 0;

    /* initial window */
    #pragma unroll
    for (int q = 0; q < NQ; ++q) {
        int c = (q << 9) + tid;
        float4 v = boxes[b * PRE + base + c];
        cx1[q] = v.x; cy1[q] = v.y; cx2[q] = v.z; cy2[q] = v.w;
        car[q] = (v.z - v.x + 1.0f) * (v.w - v.y + 1.0f);
        wb[0][c] = v.x; wb[1][c] = v.y; wb[2][c] = v.z; wb[3][c] = v.w; wb[4][c] = car[q];
    }
    if (tid < WW64) msk[0][tid] = ~0ULL;  /* PRE > WSZ: first window fully valid */
    __syncthreads();

    for (;;) {
        /* find-next-live >= cur (uniform): lanes 0-15 mirror the 16 words */
        int w = lane & 15;
        unsigned long long v = msk[p][w];
        unsigned long long cw0 = msk[p][wave];        /* my q=0 word */
        unsigned long long cw1 = msk[p][8 + wave];    /* my q=1 word */
        int lo = w << 6;
        if (lo + 64 <= cur) v = 0;
        else if (lo < cur) v &= (~0ULL << (cur - lo));
        unsigned wm = (unsigned)__ballot(v != 0) & 0xFFFFu;

        if (wm == 0) {
            /* window exhausted -> advance (or done) */
            base += WSZ;
            if (base >= PRE) break;
            __syncthreads();               /* seal msk/wb before rewrite */
            #pragma unroll
            for (int q = 0; q < NQ; ++q) {
                int c = (q << 9) + tid;
                int g = base + c; if (g > PRE - 1) g = PRE - 1;
                float4 vv = boxes[b * PRE + g];
                cx1[q] = vv.x; cy1[q] = vv.y; cx2[q] = vv.z; cy2[q] = vv.w;
                car[q] = (vv.z - vv.x + 1.0f) * (vv.w - vv.y + 1.0f);
                wb[0][c] = vv.x; wb[1][c] = vv.y; wb[2][c] = vv.z; wb[3][c] = vv.w; wb[4][c] = car[q];
            }
            int valid = PRE - base; if (valid > WSZ) valid = WSZ;
            bool dead0 = false, dead1 = false;
            for (int k = 0; k < cnt; ++k) {           /* suppress vs all kept */
                float kx1 = kb[k][0], ky1 = kb[k][1], kx2 = kb[k][2], ky2 = kb[k][3], ka = kb[k][4];
                dead0 = dead0 || iou_gt(kx1,ky1,kx2,ky2,ka, cx1[0],cy1[0],cx2[0],cy2[0],car[0]);
                dead1 = dead1 || iou_gt(kx1,ky1,kx2,ky2,ka, cx1[1],cy1[1],cx2[1],cy2[1],car[1]);
            }
            {
                int c0_ = tid;        bool a0_ = (c0_ < valid) && !dead0;
                int c1_ = 512 + tid;  bool a1_ = (c1_ < valid) && !dead1;
                unsigned long long ab0 = __ballot(a0_);
                unsigned long long ab1 = __ballot(a1_);
                if (lane == 0) { msk[p][wave] = ab0; msk[p][8 + wave] = ab1; }
            }
            cur = 0;
            __syncthreads();
            continue;
        }

        /* first two nonzero words -> candidate pool (complete live coverage) */
        int w0 = __ffs(wm) - 1;
        unsigned wmr = wm & (wm - 1);
        int w1 = wmr ? (__ffs(wmr) - 1) : 0;
        unsigned long long vv0 = __shfl(v, w0);
        unsigned long long vv1t = __shfl(v, w1);
        unsigned long long vv1 = wmr ? vv1t : 0ULL;

        /* extract up to 8 candidate indices in ascending order (uniform) */
        unsigned long long a0 = vv0, a1 = vv1;
        int nc = 0, last = 0;
        int c0, c1, c2, c3, c4, c5, c6, c7;
        #define EXTRACT(ck) { \
            unsigned long long src = a0 ? a0 : a1; \
            int wsel = a0 ? w0 : w1; \
            bool has = (src != 0ULL); \
            unsigned long long safe = has ? src : 1ULL; \
            int cand = (wsel << 6) + (__ffsll((long long)safe) - 1); \
            ck = has ? cand : last; last = ck; nc += has ? 1 : 0; \
            unsigned long long na0 = a0 ? (a0 & (a0 - 1)) : 0ULL; \
            unsigned long long na1 = a0 ? a1 : (a1 & (a1 - 1)); \
            a0 = na0; a1 = na1; }
        EXTRACT(c0) EXTRACT(c1) EXTRACT(c2) EXTRACT(c3)
        EXTRACT(c4) EXTRACT(c5) EXTRACT(c6) EXTRACT(c7)
        #undef EXTRACT

        /* pairwise suppression relation: lane L<28 handles pair (i<j) */
        int L = lane;
        float fj = sqrtf(1.0f + 8.0f * (float)L);
        int pj = (int)((1.0f + fj) * 0.5f);
        if (pj > 7) pj = 7;
        int pi = L - ((pj * (pj - 1)) >> 1);
        if (pi < 0) pi = 0; if (pi > 7) pi = 7;
        int ci = sel8(pi, c0, c1, c2, c3, c4, c5, c6, c7);
        int cj = sel8(pj, c0, c1, c2, c3, c4, c5, c6, c7);
        bool pg = false;
        if (L < 28 && pi < pj) {
            pg = iou_gt(wb[0][ci], wb[1][ci], wb[2][ci], wb[3][ci], wb[4][ci],
                        wb[0][cj], wb[1][cj], wb[2][cj], wb[3][cj], wb[4][cj]);
        }
        unsigned P = (unsigned)__ballot(pg) & 0x0FFFFFFFu;

        /* scalar greedy chain over candidates (exact reference order) */
        unsigned keepm = 1u;
        #pragma unroll
        for (int j = 1; j < 8; ++j) {
            int basej = (j * (j - 1)) >> 1;
            unsigned supbits = (P >> basej) & keepm & ((1u << j) - 1u);
            bool alive = (j < nc) && (supbits == 0);
            if (alive) keepm |= (1u << j);
        }
        int nkeep = __popc(keepm);
        int allowed = POST - cnt;
        bool full = (nkeep >= allowed);

        /* emit keeps (LDS only) + accumulate suppression vs my window boxes */
        bool dead0 = false, dead1 = false;
        #define STEP(j, cj_) if ((keepm >> (j)) & 1u) { \
            int r = __popc(keepm & ((1u << (j)) - 1u)); \
            if (r < allowed) { \
                float kx1 = wb[0][cj_], ky1 = wb[1][cj_], kx2 = wb[2][cj_], \
                      ky2 = wb[3][cj_], ka = wb[4][cj_]; \
                if (tid == (j)) { \
                    kb[cnt + r][0] = kx1; kb[cnt + r][1] = ky1; kb[cnt + r][2] = kx2; \
                    kb[cnt + r][3] = ky2; kb[cnt + r][4] = ka; } \
                if (!full) { \
                    dead0 |= (tid > cj_) && iou_gt(kx1,ky1,kx2,ky2,ka, \
                                cx1[0],cy1[0],cx2[0],cy2[0],car[0]); \
                    dead1 |= (512 + tid > cj_) && iou_gt(kx1,ky1,kx2,ky2,ka, \
                                cx1[1],cy1[1],cx2[1],cy2[1],car[1]); } } }
        STEP(0, c0) STEP(1, c1) STEP(2, c2) STEP(3, c3)
        STEP(4, c4) STEP(5, c5) STEP(6, c6) STEP(7, c7)
        #undef STEP

        cnt += full ? allowed : nkeep;
        if (cnt >= POST) break;

        unsigned long long sb0 = __ballot(dead0);
        unsigned long long sb1 = __ballot(dead1);
        if (lane == 0) {
            msk[p ^ 1][wave] = cw0 & ~sb0;
            msk[p ^ 1][8 + wave] = cw1 & ~sb1;
        }
        cur = last + 1;
        p ^= 1;
        __syncthreads();
    }

    /* single writeback: rows [0,cnt) from kb, rows [cnt,POST) zero */
    __syncthreads();
    for (int idx = tid; idx < POST * 5; idx += NMS_T) {
        int row = idx / 5;
        int col = idx - row * 5;
        float val = 0.0f;
        if (row < cnt) val = (col == 0) ? (float)b : kb[row][col - 1];
        out[(size_t)b * POST * 5 + idx] = val;
    }
}

extern "C" void kernel_launch(void* const* d_in, const int* in_sizes, int n_in,
                              void* d_out, int out_size, void* d_ws, size_t ws_size,
                              hipStream_t stream) {
    const float* scores  = (const float*)d_in[0];
    const float* deltas  = (const float*)d_in[1];
    const float* anchors = (const float*)d_in[2];
    const int*   imw     = (const int*)d_in[3];
    const int*   imh     = (const int*)d_in[4];
    float* out = (float*)d_out;
    char* ws = (char*)d_ws;

    unsigned long long* keys   = (unsigned long long*)(ws + KEYS_OFF);
    unsigned*           hist   = (unsigned*)(ws + HIST_OFF);
    unsigned*           binfo  = (unsigned*)(ws + BINFO_OFF);
    unsigned*           selcnt = (unsigned*)(ws + SELCNT_OFF);
    unsigned long long* selk   = (unsigned long long*)(ws + SELK_OFF);
    unsigned*           selidx = (unsigned*)(ws + SELIDX_OFF);
    float4*             boxes  = (float4*)(ws + BOXES_OFF);

    /* zero hist + binfo + selcnt (ws is poisoned before every call) */
    hipMemsetAsync(ws + HIST_OFF, 0, HIST_BYTES + BINFO_BYTES + SELCNT_BYTES, stream);

    keys_kernel<<<(BB * NN + 255) / 256, 256, 0, stream>>>(scores, keys, hist);
    scan_kernel<<<BB, 1024, 0, stream>>>(hist, binfo);
    compact_kernel<<<(BB * NN + 255) / 256, 256, 0, stream>>>(keys, binfo, selcnt, selk);
    rank_kernel<<<BB * 32, 256, 0, stream>>>(selcnt, selk, selidx);
    box_kernel<<<(BB * PRE + 255) / 256, 256, 0, stream>>>(selidx, deltas, anchors, imw, imh, boxes);
    nms_kernel<<<BB, NMS_T, 0, stream>>>(boxes, out);
}

// Round 6
// 191.402 us; speedup vs baseline: 5.4015x; 2.0819x over previous
//
#include <hip/hip_runtime.h>
#include <math.h>

#pragma clang fp contract(off)

#define BB 8
#define AA 9
#define NPIX 4096          /* 64*64 */
#define NN (NPIX*AA)       /* 36864 */
#define PRE 6000
#define POST 300
#define SELCAP 8192
#define NMS_T 512

/* ---- workspace layout (bytes) ----
   HIST doubles as BINPRE: scan converts counts -> exclusive prefix in place. */
#define HIST_OFF   0ULL                /* 8*65536*4 = 2,097,152 */
#define BINOFF_OFF 2097152ULL          /* 8*65536*4 = 2,097,152 (per-bin scatter counters) */
#define BINFO_OFF  4194304ULL          /* 8*2*4 = 64  [T, cnt] per batch */
#define SELK_OFF   4194368ULL          /* 8*8192*8 = 524,288 */
#define SELIDX_OFF 4718656ULL          /* 8*6000*4 = 192,000 */
#define ZERO_BYTES (2097152ULL + 2097152ULL + 64ULL)   /* hist+binoff+binfo contiguous */

__device__ __forceinline__ unsigned score_key(float s) {
    unsigned fb = __float_as_uint(s);
    unsigned u = (fb & 0x80000000u) ? ~fb : (fb | 0x80000000u); /* ascending = float ascending */
    return ~u;                                                  /* ascending = score descending */
}

/* 1) histogram of 16-bit key prefixes. t -> (b, a, pix) so score reads coalesce. */
__global__ void hist_kernel(const float* __restrict__ scores, unsigned* __restrict__ hist) {
    int t = blockIdx.x * blockDim.x + threadIdx.x;
    if (t >= BB * NN) return;
    int b = t / NN;
    int r = t - b * NN;                 /* r = a*4096 + pix */
    float s = scores[(size_t)(b * (2*AA) + AA) * NPIX + r];
    unsigned k = score_key(s);
    atomicAdd(&hist[((unsigned)b << 16) + (k >> 16)], 1u);
}

/* 2) per-batch: hist -> exclusive prefix IN PLACE (binpre), find boundary bin T
   and total count cnt through T. Thread's 64 bins kept in regs (unrolled). */
__global__ __launch_bounds__(1024) void scan_kernel(unsigned* __restrict__ hist,
                                                    unsigned* __restrict__ binfo) {
    int b = blockIdx.x;
    int tid = threadIdx.x;
    unsigned* h = hist + ((size_t)b << 16);
    unsigned base = tid * 64;
    unsigned hv[64];
    unsigned s = 0;
    #pragma unroll
    for (int q = 0; q < 64; ++q) { hv[q] = h[base + q]; s += hv[q]; }
    __shared__ unsigned psum[1024];
    psum[tid] = s;
    __syncthreads();
    for (int off = 1; off < 1024; off <<= 1) {
        unsigned v = (tid >= off) ? psum[tid - off] : 0u;
        __syncthreads();
        psum[tid] += v;
        __syncthreads();
    }
    unsigned incl = psum[tid];
    unsigned excl = incl - s;
    /* write exclusive prefixes back in place (own chunk only -> no hazard) */
    unsigned run = excl;
    #pragma unroll
    for (int q = 0; q < 64; ++q) { unsigned c = hv[q]; h[base + q] = run; run += c; }
    /* boundary bin: rank PRE-1 falls in my chunk */
    if (excl <= (PRE - 1) && (PRE - 1) < incl) {
        unsigned c = excl, T = base, tot = incl;
        bool found = false;
        #pragma unroll
        for (int q = 0; q < 64; ++q) {
            if (!found && (PRE - 1) < c + hv[q]) { T = base + q; tot = c + hv[q]; found = true; }
            c += hv[q];
        }
        binfo[b * 2 + 0] = T;
        binfo[b * 2 + 1] = tot;      /* cnt = #keys in bins <= T  (6000..~6100) */
    }
}

/* 3) scatter selected keys grouped by bin: slot = binpre[bin] + intra (per-bin atomic).
   Key recomputed from scores (keys array eliminated). Intra-bin order arbitrary. */
__global__ void compact_kernel(const float* __restrict__ scores,
                               const unsigned* __restrict__ binfo,
                               const unsigned* __restrict__ binpre,
                               unsigned* __restrict__ binoff,
                               unsigned long long* __restrict__ selk) {
    int t = blockIdx.x * blockDim.x + threadIdx.x;
    if (t >= BB * NN) return;
    int b = t / NN;
    int r = t - b * NN;
    float s = scores[(size_t)(b * (2*AA) + AA) * NPIX + r];
    unsigned k = score_key(s);
    unsigned bin = k >> 16;
    unsigned T = binfo[b * 2 + 0];
    if (bin <= T) {
        int a = r >> 12;
        int pix = r & 4095;
        int i = pix * AA + a;            /* reference flat index */
        unsigned long long key = ((unsigned long long)k << 32) | (unsigned)i;
        unsigned pos = binpre[((unsigned)b << 16) + bin]
                     + atomicAdd(&binoff[((unsigned)b << 16) + bin], 1u);
        if (pos < SELCAP) selk[((size_t)b << 13) + pos] = key;
    }
}

/* 4) exact rank, within-bin only (~50 iters vs 6100 in R5 — R5 post-mortem:
   global rank loop was ~80us at 4 waves/CU). Keys staged in LDS, 32 blocks/batch. */
__global__ __launch_bounds__(256) void rank_kernel(const unsigned* __restrict__ binfo,
                                                   const unsigned* __restrict__ binpre,
                                                   const unsigned* __restrict__ binoff,
                                                   const unsigned long long* __restrict__ selk,
                                                   unsigned* __restrict__ selidx) {
    __shared__ unsigned long long skl[SELCAP];   /* 64 KB */
    int b = blockIdx.x >> 5;
    int chunk = blockIdx.x & 31;
    unsigned cnt = binfo[b * 2 + 1];
    if (cnt > SELCAP) cnt = SELCAP;
    const unsigned long long* src = selk + ((size_t)b << 13);
    for (int i = threadIdx.x; i < (int)cnt; i += 256) skl[i] = src[i];
    __syncthreads();
    int s = (chunk << 8) + threadIdx.x;
    if (s >= (int)cnt) return;
    unsigned long long key = skl[s];
    unsigned bin = (unsigned)(key >> 48);
    unsigned start = binpre[((unsigned)b << 16) + bin];
    unsigned n = binoff[((unsigned)b << 16) + bin];
    if (start + n > SELCAP) n = (start < SELCAP) ? (SELCAP - start) : 0;
    unsigned rank = start;
    for (unsigned j = 0; j < n; ++j) rank += (skl[start + j] < key) ? 1u : 0u;
    if (rank < PRE) selidx[b * PRE + rank] = (unsigned)(key & 0xFFFFFFFFu);
}

/* Exact, division-free replica of the reference suppression test:
   RN_f32(inter/uni) > 0.7f  <=>  (double)inter >= (0.7f + 2^-25) * (double)uni
   (25-bit x 24-bit mantissas -> f64 product exact; tie rounds-to-even UP). */
__device__ __forceinline__ bool iou_gt(float ax1, float ay1, float ax2, float ay2, float aa,
                                       float bx1_, float by1_, float bx2_, float by2_, float ab) {
    float xx1 = fmaxf(ax1, bx1_);
    float yy1 = fmaxf(ay1, by1_);
    float xx2 = fminf(ax2, bx2_);
    float yy2 = fminf(ay2, by2_);
    float iw = fmaxf(xx2 - xx1 + 1.0f, 0.0f);
    float ih = fmaxf(yy2 - yy1 + 1.0f, 0.0f);
    float inter = iw * ih;
    float uni = (aa + ab) - inter;
    return (double)inter >= 0x1.666667p-1 * (double)uni;
}

/* 5) batched on-demand greedy NMS + lazy box decode, one block/batch, 512 threads.
   R5 post-mortem: window suppression = 300 keeps x 1024-box IoU = VALU-bound
   (~100us on 8 CUs). Here: NO window, NO mask. Per 64-candidate batch:
   - lanes decode boxes cur..cur+63 (box_kernel fused, only ~M boxes decoded)
   - dead-vs-kept: waves split kept list mod 8, ballot-combine (64 x cnt IoUs
     total, vs kept only)
   - blind 64x64 pairwise (2016 IoUs over 512 threads)
   - uniform 64-step scalar chain = exact greedy order.
   Total IoUs ~ sum(64*cnt) ~= 120K vs R5's 300K+, and decays with M. */
__global__ __launch_bounds__(NMS_T) void nms_kernel(const unsigned* __restrict__ selidx,
                                                    const float* __restrict__ deltas,
                                                    const float* __restrict__ anchors,
                                                    const int* __restrict__ imw,
                                                    const int* __restrict__ imh,
                                                    float* __restrict__ out) {
    int b = blockIdx.x;
    int tid = threadIdx.x;
    int wave = tid >> 6;
    int lane = tid & 63;
    __shared__ float kb[POST][5];            /* kept boxes: x1,y1,x2,y2,area */
    __shared__ float cnd[5][64];             /* current 64 candidates */
    __shared__ unsigned long long sup[64];   /* sup[j]: bits i<j that suppress j */
    __shared__ unsigned long long deadw[8];

    float fw = (float)(imw[0] - 1);
    float fh = (float)(imh[0] - 1);

    int cur = 0, K = 0;
    for (;;) {
        /* decode candidates cur..cur+63 (wave-0 lanes), zero sup */
        if (tid < 64) {
            int g = cur + tid;
            unsigned idx = selidx[b * PRE + ((g < PRE) ? g : (PRE - 1))];
            int a = idx % AA;
            int pix = idx / AA;
            int wq = pix & 63;
            int hq = pix >> 6;
            float sx = (float)(wq * 16);
            float sy = (float)(hq * 16);
            float ax1 = anchors[a * 4 + 0] + sx;
            float ay1 = anchors[a * 4 + 1] + sy;
            float ax2 = anchors[a * 4 + 2] + sx;
            float ay2 = anchors[a * 4 + 3] + sy;
            float aw = ax2 - ax1 + 1.0f;
            float ah = ay2 - ay1 + 1.0f;
            float acx = ax1 + 0.5f * aw;
            float acy = ay1 + 0.5f * ah;
            size_t dbase = ((size_t)b * (4*AA) + (size_t)a * 4) * NPIX + pix;
            float d0 = deltas[dbase + 0*NPIX];
            float d1 = deltas[dbase + 1*NPIX];
            float d2 = deltas[dbase + 2*NPIX];
            float d3 = deltas[dbase + 3*NPIX];
            float pcx = d0 * aw + acx;
            float pcy = d1 * ah + acy;
            float pw = expf(d2) * aw;
            float ph = expf(d3) * ah;
            float x1 = fminf(fmaxf(pcx - 0.5f * pw, 0.0f), fw);
            float y1 = fminf(fmaxf(pcy - 0.5f * ph, 0.0f), fh);
            float x2 = fminf(fmaxf(pcx + 0.5f * pw, 0.0f), fw);
            float y2 = fminf(fmaxf(pcy + 0.5f * ph, 0.0f), fh);
            cnd[0][tid] = x1; cnd[1][tid] = y1; cnd[2][tid] = x2; cnd[3][tid] = y2;
            cnd[4][tid] = (x2 - x1 + 1.0f) * (y2 - y1 + 1.0f);
            sup[tid] = 0ULL;
        }
        __syncthreads();

        /* my candidate (lane <-> candidate), conflict-free LDS reads */
        float mx1 = cnd[0][lane], my1 = cnd[1][lane], mx2 = cnd[2][lane],
              my2 = cnd[3][lane], mar = cnd[4][lane];

        /* dead vs kept list: wave w checks keeps w, w+8, ... */
        bool dead = (cur + lane >= PRE);
        for (int k = wave; k < K; k += 8)
            dead = dead || iou_gt(kb[k][0], kb[k][1], kb[k][2], kb[k][3], kb[k][4],
                                  mx1, my1, mx2, my2, mar);
        unsigned long long bal = __ballot(dead);
        if (lane == 0) deadw[wave] = bal;

        /* blind pairwise among the 64 candidates: 2016 pairs / 512 threads */
        #pragma unroll
        for (int qq = 0; qq < 4; ++qq) {
            int p = tid + (qq << 9);
            if (p < 2016) {
                int j = (int)((1.0f + sqrtf(1.0f + 8.0f * (float)p)) * 0.5f);
                while ((j * (j - 1)) / 2 > p) --j;
                while (((j + 1) * j) / 2 <= p) ++j;
                int i = p - (j * (j - 1)) / 2;
                bool g = iou_gt(cnd[0][i], cnd[1][i], cnd[2][i], cnd[3][i], cnd[4][i],
                                cnd[0][j], cnd[1][j], cnd[2][j], cnd[3][j], cnd[4][j]);
                if (g) atomicOr(&sup[j], 1ULL << i);
            }
        }
        __syncthreads();

        /* uniform greedy chain over the 64 candidates (exact reference order) */
        unsigned long long dk = deadw[0] | deadw[1] | deadw[2] | deadw[3]
                              | deadw[4] | deadw[5] | deadw[6] | deadw[7];
        unsigned long long keptb = 0ULL;
        for (int j = 0; j < 64; ++j) {
            bool alive = !((dk >> j) & 1ULL) && ((sup[j] & keptb) == 0ULL);
            if (alive) keptb |= (1ULL << j);
        }
        int nkeep = __popcll(keptb);
        int take = POST - K; if (nkeep < take) take = nkeep;

        /* commit keeps (LDS only; out written once at the end) */
        if (tid < 64 && ((keptb >> tid) & 1ULL)) {
            int rnk = __popcll(keptb & ((1ULL << tid) - 1ULL));
            if (rnk < take) {
                kb[K + rnk][0] = mx1; kb[K + rnk][1] = my1; kb[K + rnk][2] = mx2;
                kb[K + rnk][3] = my2; kb[K + rnk][4] = mar;
            }
        }
        K += take;
        cur += 64;
        __syncthreads();
        if (K >= POST || cur >= PRE) break;
    }

    /* single writeback: rows [0,K) from kb, rows [K,POST) zero */
    for (int idx = tid; idx < POST * 5; idx += NMS_T) {
        int row = idx / 5;
        int col = idx - row * 5;
        float val = 0.0f;
        if (row < K) val = (col == 0) ? (float)b : kb[row][col - 1];
        out[(size_t)b * POST * 5 + idx] = val;
    }
}

extern "C" void kernel_launch(void* const* d_in, const int* in_sizes, int n_in,
                              void* d_out, int out_size, void* d_ws, size_t ws_size,
                              hipStream_t stream) {
    const float* scores  = (const float*)d_in[0];
    const float* deltas  = (const float*)d_in[1];
    const float* anchors = (const float*)d_in[2];
    const int*   imw     = (const int*)d_in[3];
    const int*   imh     = (const int*)d_in[4];
    float* out = (float*)d_out;
    char* ws = (char*)d_ws;

    unsigned*           hist   = (unsigned*)(ws + HIST_OFF);   /* -> binpre after scan */
    unsigned*           binoff = (unsigned*)(ws + BINOFF_OFF);
    unsigned*           binfo  = (unsigned*)(ws + BINFO_OFF);
    unsigned long long* selk   = (unsigned long long*)(ws + SELK_OFF);
    unsigned*           selidx = (unsigned*)(ws + SELIDX_OFF);

    /* zero hist + binoff + binfo (contiguous; ws is poisoned before every call) */
    hipMemsetAsync(ws + HIST_OFF, 0, ZERO_BYTES, stream);

    hist_kernel<<<(BB * NN + 255) / 256, 256, 0, stream>>>(scores, hist);
    scan_kernel<<<BB, 1024, 0, stream>>>(hist, binfo);
    compact_kernel<<<(BB * NN + 255) / 256, 256, 0, stream>>>(scores, binfo, hist, binoff, selk);
    rank_kernel<<<BB * 32, 256, 0, stream>>>(binfo, hist, binoff, selk, selidx);
    nms_kernel<<<BB, NMS_T, 0, stream>>>(selidx, deltas, anchors, imw, imh, out);
}

// Round 7
// 189.480 us; speedup vs baseline: 5.4563x; 1.0101x over previous
//
#include <hip/hip_runtime.h>
#include <math.h>

#pragma clang fp contract(off)

#define BB 8
#define AA 9
#define NPIX 4096          /* 64*64 */
#define NN (NPIX*AA)       /* 36864 */
#define PRE 6000
#define POST 300
#define SELCAP 8192
#define NBIN 16384         /* 14-bit prefix bins (LDS-histogram-sized) */
#define BSH 18             /* key32 >> 18 -> 14-bit bin */
#define NMS_T 512
#define NDEC 12            /* candidates per thread: 512*12 = 6144 >= PRE */

/* ---- workspace layout (bytes) ---- */
#define BINPRE_OFF 0ULL                      /* 8*16384*4 = 524,288 */
#define BINOFF_OFF 524288ULL                 /* 8*16384*4 = 524,288 */
#define BINFO_OFF  1048576ULL                /* 8*2*4 = 64 */
#define SELK_OFF   1048640ULL                /* 8*8192*8 = 524,288 (8-aligned) */
#define SELIDX_OFF 1572928ULL                /* 8*6000*4 = 192,000 */

__device__ __forceinline__ unsigned score_key(float s) {
    unsigned fb = __float_as_uint(s);
    unsigned u = (fb & 0x80000000u) ? ~fb : (fb | 0x80000000u); /* ascending = float ascending */
    return ~u;                                                  /* ascending = score descending */
}

/* swizzled LDS word for bin bi: contiguous 16-bin chunks land at stride-1024
   words -> conflict-free per-thread readback */
#define HW(bi) ((((bi) & 15) << 10) | ((bi) >> 4))

/* 1) fused histogram + scan, one block per batch (R6 post-mortem: separate
   memset+hist+scan cost ~60-80us; 20+ 16-wave barriers in scan). LDS hist,
   shuffle scan (2 barriers), writes binpre (exclusive prefix), zeroes binoff,
   finds boundary bin T + cnt. */
__global__ __launch_bounds__(1024) void hist_scan_kernel(const float* __restrict__ scores,
                                                         unsigned* __restrict__ binpre,
                                                         unsigned* __restrict__ binoff,
                                                         unsigned* __restrict__ binfo) {
    __shared__ unsigned hb[NBIN];            /* 64 KB */
    int b = blockIdx.x;
    int tid = threadIdx.x;
    int wave = tid >> 6, lane = tid & 63;
    for (int j = tid; j < NBIN; j += 1024) hb[j] = 0;
    __syncthreads();
    const float* sc = scores + (size_t)(b * (2*AA) + AA) * NPIX;
    #pragma unroll
    for (int q = 0; q < 36; ++q) {
        float s = sc[tid + (q << 10)];
        atomicAdd(&hb[HW(score_key(s) >> BSH)], 1u);
    }
    __syncthreads();
    unsigned hv[16];
    unsigned ssum = 0;
    #pragma unroll
    for (int j = 0; j < 16; ++j) { hv[j] = hb[tid + (j << 10)]; ssum += hv[j]; }
    __syncthreads();                         /* hb now reusable */
    /* wave-inclusive shuffle scan of per-thread sums */
    unsigned x = ssum;
    #pragma unroll
    for (int d = 1; d < 64; d <<= 1) { unsigned y = __shfl_up(x, (unsigned)d, 64); if (lane >= d) x += y; }
    if (lane == 63) hb[wave] = x;            /* wave totals */
    __syncthreads();
    if (tid == 0) {
        unsigned run = 0;
        for (int w = 0; w < 16; ++w) { unsigned c = hb[w]; hb[16 + w] = run; run += c; }
    }
    __syncthreads();
    unsigned gexcl = hb[16 + wave] + (x - ssum);
    /* write exclusive prefixes + zero binoff */
    unsigned* bp = binpre + ((size_t)b << 14);
    unsigned* bo = binoff + ((size_t)b << 14);
    unsigned run = gexcl;
    #pragma unroll
    for (int j = 0; j < 16; ++j) { bp[tid * 16 + j] = run; run += hv[j]; }
    for (int j = tid; j < NBIN; j += 1024) bo[j] = 0;
    /* boundary bin: rank PRE-1 in my 16-bin chunk */
    unsigned gincl = gexcl + ssum;
    if (gexcl <= (PRE - 1) && (PRE - 1) < gincl) {
        unsigned c = gexcl, T = tid * 16, tot = gincl;
        bool f = false;
        #pragma unroll
        for (int j = 0; j < 16; ++j) {
            if (!f && (PRE - 1) < c + hv[j]) { T = tid * 16 + j; tot = c + hv[j]; f = true; }
            c += hv[j];
        }
        binfo[b * 2 + 0] = T;
        binfo[b * 2 + 1] = tot;              /* cnt in bins <= T (6000..~6600) */
    }
}

/* 2) scatter selected keys grouped by bin (slot = binpre[bin] + per-bin atomic) */
__global__ void compact_kernel(const float* __restrict__ scores,
                               const unsigned* __restrict__ binfo,
                               const unsigned* __restrict__ binpre,
                               unsigned* __restrict__ binoff,
                               unsigned long long* __restrict__ selk) {
    int t = blockIdx.x * blockDim.x + threadIdx.x;
    if (t >= BB * NN) return;
    int b = t / NN;
    int r = t - b * NN;
    float s = scores[(size_t)(b * (2*AA) + AA) * NPIX + r];
    unsigned k = score_key(s);
    unsigned bin = k >> BSH;
    if (bin <= binfo[b * 2 + 0]) {
        int a = r >> 12;
        int pix = r & 4095;
        int i = pix * AA + a;                /* reference flat index */
        unsigned long long key = ((unsigned long long)k << 32) | (unsigned)i;
        unsigned pos = binpre[((size_t)b << 14) + bin]
                     + atomicAdd(&binoff[((size_t)b << 14) + bin], 1u);
        if (pos < SELCAP) selk[((size_t)b << 13) + pos] = key;
    }
}

/* 3) exact rank within own bin (keys LDS-staged; 32 blocks/batch) */
__global__ __launch_bounds__(256) void rank_kernel(const unsigned* __restrict__ binfo,
                                                   const unsigned* __restrict__ binpre,
                                                   const unsigned* __restrict__ binoff,
                                                   const unsigned long long* __restrict__ selk,
                                                   unsigned* __restrict__ selidx) {
    __shared__ unsigned long long skl[SELCAP];   /* 64 KB */
    int b = blockIdx.x >> 5;
    int chunk = blockIdx.x & 31;
    unsigned cnt = binfo[b * 2 + 1];
    if (cnt > SELCAP) cnt = SELCAP;
    const unsigned long long* src = selk + ((size_t)b << 13);
    for (int i = threadIdx.x; i < (int)cnt; i += 256) skl[i] = src[i];
    __syncthreads();
    int s = (chunk << 8) + threadIdx.x;
    if (s >= (int)cnt) return;
    unsigned long long key = skl[s];
    unsigned bin = (unsigned)(key >> (32 + BSH));
    unsigned start = binpre[((size_t)b << 14) + bin];
    unsigned n = binoff[((size_t)b << 14) + bin];
    if (start + n > SELCAP) n = (start < SELCAP) ? (SELCAP - start) : 0;
    unsigned rank = start;
    for (unsigned j = 0; j < n; ++j) rank += (skl[start + j] < key) ? 1u : 0u;
    if (rank < PRE) selidx[b * PRE + rank] = (unsigned)(key & 0xFFFFFFFFu);
}

/* Exact, division-free replica of the reference suppression test:
   RN_f32(inter/uni) > 0.7f  <=>  (double)inter >= (0.7f + 2^-25) * (double)uni
   (25-bit x 24-bit mantissas -> f64 product exact; tie rounds-to-even UP). */
__device__ __forceinline__ bool iou_gt(float ax1, float ay1, float ax2, float ay2, float aa,
                                       float bx1_, float by1_, float bx2_, float by2_, float ab) {
    float xx1 = fmaxf(ax1, bx1_);
    float yy1 = fmaxf(ay1, by1_);
    float xx2 = fminf(ax2, bx2_);
    float yy2 = fminf(ay2, by2_);
    float iw = fmaxf(xx2 - xx1 + 1.0f, 0.0f);
    float ih = fmaxf(yy2 - yy1 + 1.0f, 0.0f);
    float inter = iw * ih;
    float uni = (aa + ab) - inter;
    return (double)inter >= 0x1.666667p-1 * (double)uni;
}

/* 4) greedy NMS, one block/batch, 512 threads.
   R6 post-mortem: 6.2K cyc/round dominated by 64 dependent LDS reads in the
   scalar chain + LDS atomicOr + in-round scattered decode. Here:
   - all 6144 candidates decoded ONCE into registers (12/thread, pipelined)
   - owning wave stages its 64 boxes reg->LDS per round (no global on path)
   - suppression rows via __ballot (no atomics)
   - chain: register row + uniform ballot loop, iters = keeps/round (~12) */
__global__ __launch_bounds__(NMS_T) void nms_kernel(const unsigned* __restrict__ selidx,
                                                    const float* __restrict__ deltas,
                                                    const float* __restrict__ anchors,
                                                    const int* __restrict__ imw,
                                                    const int* __restrict__ imh,
                                                    float* __restrict__ out) {
    int b = blockIdx.x;
    int tid = threadIdx.x;
    int wave = tid >> 6, lane = tid & 63;
    __shared__ float4 cnd4[64];
    __shared__ float cnda[64];
    __shared__ float4 kb4[POST];
    __shared__ float kba[POST];
    __shared__ unsigned long long srow[64];
    __shared__ unsigned long long deadw[8];

    float fw = (float)(imw[0] - 1);
    float fh = (float)(imh[0] - 1);

    /* decode my 12 candidates (c = q*512 + tid) into registers */
    float dx1[NDEC], dy1[NDEC], dx2[NDEC], dy2[NDEC], dar[NDEC];
    #pragma unroll
    for (int q = 0; q < NDEC; ++q) {
        int c = (q << 9) + tid;
        int g = (c < PRE) ? c : (PRE - 1);
        unsigned idx = selidx[b * PRE + g];
        int a = idx % AA;
        int pix = idx / AA;
        int wq = pix & 63;
        int hq = pix >> 6;
        float sx = (float)(wq * 16);
        float sy = (float)(hq * 16);
        float ax1 = anchors[a * 4 + 0] + sx;
        float ay1 = anchors[a * 4 + 1] + sy;
        float ax2 = anchors[a * 4 + 2] + sx;
        float ay2 = anchors[a * 4 + 3] + sy;
        float aw = ax2 - ax1 + 1.0f;
        float ah = ay2 - ay1 + 1.0f;
        float acx = ax1 + 0.5f * aw;
        float acy = ay1 + 0.5f * ah;
        size_t dbase = ((size_t)b * (4*AA) + (size_t)a * 4) * NPIX + pix;
        float d0 = deltas[dbase + 0*NPIX];
        float d1 = deltas[dbase + 1*NPIX];
        float d2 = deltas[dbase + 2*NPIX];
        float d3 = deltas[dbase + 3*NPIX];
        float pcx = d0 * aw + acx;
        float pcy = d1 * ah + acy;
        float pw = expf(d2) * aw;
        float ph = expf(d3) * ah;
        float x1 = fminf(fmaxf(pcx - 0.5f * pw, 0.0f), fw);
        float y1 = fminf(fmaxf(pcy - 0.5f * ph, 0.0f), fh);
        float x2 = fminf(fmaxf(pcx + 0.5f * pw, 0.0f), fw);
        float y2 = fminf(fmaxf(pcy + 0.5f * ph, 0.0f), fh);
        dx1[q] = x1; dy1[q] = y1; dx2[q] = x2; dy2[q] = y2;
        dar[q] = (x2 - x1 + 1.0f) * (y2 - y1 + 1.0f);
    }

    int cur = 0, K = 0;
    for (;;) {
        /* owning wave stages candidates cur..cur+63 from registers to LDS */
        int owner = (cur >> 6) & 7;
        int q = cur >> 9;                  /* wave-uniform register slot */
        if (wave == owner) {
            float x1 = dx1[0], y1 = dy1[0], x2 = dx2[0], y2 = dy2[0], ar_ = dar[0];
            #pragma unroll
            for (int qq = 1; qq < NDEC; ++qq)
                if (qq == q) { x1 = dx1[qq]; y1 = dy1[qq]; x2 = dx2[qq]; y2 = dy2[qq]; ar_ = dar[qq]; }
            cnd4[lane] = make_float4(x1, y1, x2, y2);
            cnda[lane] = ar_;
        }
        __syncthreads();

        float4 mc = cnd4[lane];            /* my candidate (lane <-> candidate) */
        float ma = cnda[lane];

        /* dead vs kept list (waves split keeps mod 8, early-exit when all dead) */
        bool dead = (cur + lane >= PRE);
        for (int k = wave; k < K; k += 8) {
            if (__all(dead)) break;
            float4 kv = kb4[k];
            float ka = kba[k];
            dead = dead || iou_gt(kv.x, kv.y, kv.z, kv.w, ka, mc.x, mc.y, mc.z, mc.w, ma);
        }
        unsigned long long db = __ballot(dead);
        if (lane == 0) deadw[wave] = db;

        /* suppression rows: wave w builds rows j = 8q2 + w via one ballot each */
        #pragma unroll
        for (int q2 = 0; q2 < 8; ++q2) {
            int j = (q2 << 3) + wave;
            float4 cj = cnd4[j];
            float aj = cnda[j];
            bool g = (lane < j) && iou_gt(mc.x, mc.y, mc.z, mc.w, ma,
                                          cj.x, cj.y, cj.z, cj.w, aj);
            unsigned long long bl = __ballot(g);
            if (lane == 0) srow[j] = bl;
        }
        __syncthreads();

        /* uniform greedy chain: iterations = keeps this round */
        unsigned long long dk = deadw[0] | deadw[1] | deadw[2] | deadw[3]
                              | deadw[4] | deadw[5] | deadw[6] | deadw[7];
        unsigned long long row = srow[lane];   /* one conflict-free LDS read */
        unsigned long long live = ~dk;
        unsigned long long keptb = 0ULL;
        int allowed = POST - K;
        while (live) {
            int f = __ffsll((long long)live) - 1;
            keptb |= (1ULL << f);
            if (__popcll(keptb) >= allowed) break;
            bool die = (row >> f) & 1ULL;
            unsigned long long dbl = __ballot(die);
            live &= ~(dbl | (1ULL << f));
        }
        int nkeep = __popcll(keptb);
        int take = (nkeep < allowed) ? nkeep : allowed;

        /* commit keeps (wave 0, LDS only) */
        if (wave == 0 && ((keptb >> lane) & 1ULL)) {
            int rnk = __popcll(keptb & ((1ULL << lane) - 1ULL));
            if (rnk < take) { kb4[K + rnk] = mc; kba[K + rnk] = ma; }
        }
        K += take;
        cur += 64;
        if (K >= POST || cur >= PRE) break;
        __syncthreads();
    }

    /* single writeback: rows [0,K) from kb, rows [K,POST) zero */
    __syncthreads();
    for (int idx = tid; idx < POST * 5; idx += NMS_T) {
        int row_ = idx / 5;
        int col = idx - row_ * 5;
        float val = 0.0f;
        if (row_ < K) {
            float4 v = kb4[row_];
            val = (col == 0) ? (float)b : (col == 1) ? v.x : (col == 2) ? v.y
                : (col == 3) ? v.z : v.w;
        }
        out[(size_t)b * POST * 5 + idx] = val;
    }
}

extern "C" void kernel_launch(void* const* d_in, const int* in_sizes, int n_in,
                              void* d_out, int out_size, void* d_ws, size_t ws_size,
                              hipStream_t stream) {
    const float* scores  = (const float*)d_in[0];
    const float* deltas  = (const float*)d_in[1];
    const float* anchors = (const float*)d_in[2];
    const int*   imw     = (const int*)d_in[3];
    const int*   imh     = (const int*)d_in[4];
    float* out = (float*)d_out;
    char* ws = (char*)d_ws;

    unsigned*           binpre = (unsigned*)(ws + BINPRE_OFF);
    unsigned*           binoff = (unsigned*)(ws + BINOFF_OFF);
    unsigned*           binfo  = (unsigned*)(ws + BINFO_OFF);
    unsigned long long* selk   = (unsigned long long*)(ws + SELK_OFF);
    unsigned*           selidx = (unsigned*)(ws + SELIDX_OFF);

    /* no memset: hist_scan fully writes binpre/binfo and zeroes binoff */
    hist_scan_kernel<<<BB, 1024, 0, stream>>>(scores, binpre, binoff, binfo);
    compact_kernel<<<(BB * NN + 255) / 256, 256, 0, stream>>>(scores, binfo, binpre, binoff, selk);
    rank_kernel<<<BB * 32, 256, 0, stream>>>(binfo, binpre, binoff, selk, selidx);
    nms_kernel<<<BB, NMS_T, 0, stream>>>(selidx, deltas, anchors, imw, imh, out);
}